// Round 10
// baseline (463.891 us; speedup 1.0000x reference)
//
#include <hip/hip_runtime.h>

typedef unsigned short u16;
typedef u16 u16x8 __attribute__((ext_vector_type(8)));
typedef u16 u16x4 __attribute__((ext_vector_type(4)));
typedef __bf16 bf16x8 __attribute__((ext_vector_type(8)));
typedef float f32x4 __attribute__((ext_vector_type(4)));

#define DEVI static __device__ __forceinline__

#define BB 32
#define NN 577
#define CC 1024
#define HH 16
#define DD 64
#define MM (BB * NN)   // 18464
#define SCALE_ 0.125f

DEVI u16 f2bf(float f) {
  union { float f; unsigned u; } v; v.f = f;
  unsigned r = v.u + 0x7FFFu + ((v.u >> 16) & 1u);
  return (u16)(r >> 16);
}
DEVI float bf2f(u16 b) {
  union { unsigned u; float f; } v; v.u = ((unsigned)b) << 16; return v.f;
}
DEVI f32x4 mfma16(u16x8 a, u16x8 b, f32x4 c) {
  return __builtin_amdgcn_mfma_f32_16x16x32_bf16(
      __builtin_bit_cast(bf16x8, a), __builtin_bit_cast(bf16x8, b), c, 0, 0, 0);
}
DEVI void gload_lds16(const u16* g, u16* l) {
  __builtin_amdgcn_global_load_lds(
      (const __attribute__((address_space(1))) void*)g,
      (__attribute__((address_space(3))) void*)l, 16, 0, 0);
}

// ---------------- fused fp32 -> bf16 convert (X, Wqkv, Wproj) ----------------
__global__ void cvt3_kernel(const float* __restrict__ X, const float* __restrict__ Wq,
                            const float* __restrict__ Wp, u16* __restrict__ Xb,
                            u16* __restrict__ Wqb, u16* __restrict__ Wpb) {
  const int nX = (MM * CC) / 4;
  const int nQ = (3 * CC * CC) / 4;
  const int nP = (CC * CC) / 4;
  const int total = nX + nQ + nP;
  int i = blockIdx.x * blockDim.x + threadIdx.x;
  int stride = gridDim.x * blockDim.x;
  for (; i < total; i += stride) {
    const float* in; u16* out; int k;
    if (i < nX)            { in = X;  out = Xb;  k = i; }
    else if (i < nX + nQ)  { in = Wq; out = Wqb; k = i - nX; }
    else                   { in = Wp; out = Wpb; k = i - nX - nQ; }
    float4 v = ((const float4*)in)[k];
    u16x4 o = { f2bf(v.x), f2bf(v.y), f2bf(v.z), f2bf(v.w) };
    ((u16x4*)out)[k] = o;
  }
}

// ---- GEMM: m97 2-barrier structure + T2 swizzle, 256x128 tile, 4 waves. ----
// Per-wave output 128x64 (acc 8x4 f32x4): 24 ds_read_b128 : 64 MFMA per
// K-tile = 1.33x better FLOP/LDS-byte and ~1.4x less VALU/FLOP than the
// 128x128 / 64x64-per-wave variant. C[M,N] = A[M,K] * Bw[N,K]^T.
// A-staging uses a single per-lane base + uniform row-steps (no per-i clamp):
// rows past M read mapped workspace garbage that only lands in C rows >= M,
// which the epilogue guard drops.
__global__ __launch_bounds__(256) void gemm_w2(
    const u16* __restrict__ A, const u16* __restrict__ Bw,
    u16* __restrict__ Cb, float* __restrict__ Cf, const float* __restrict__ bias,
    int M, int N, int K, int MT, int NT)
{
  __shared__ u16 Als[256 * 64];   // 32 KB
  __shared__ u16 Bls[128 * 64];   // 16 KB

  // bijective XCD swizzle (m204)
  int nwg = MT * NT;
  int orig = blockIdx.x;
  int q = nwg >> 3, r = nwg & 7;
  int xcd = orig & 7, idx = orig >> 3;
  int wg = (xcd < r ? xcd * (q + 1) : r * (q + 1) + (xcd - r) * q) + idx;
  int mt = wg / NT, nt = wg % NT;

  const int t = threadIdx.x, lane = t & 63, w = t >> 6;
  const int wr = (w >> 1) * 128, wc = (w & 1) * 64;
  const int fr = lane & 15, fg = lane >> 4;
  const int m0 = mt * 256, n0 = nt * 128;

  f32x4 acc[8][4] = {};

  // staging: LDS[row][c] = G[row][c ^ (row&7)] (16B chunks), linear dest.
  const int swcol = ((lane & 7) ^ ((lane >> 3) & 7)) * 8;
  const int lrow = w * 8 + (lane >> 3);
  const u16* pA = A + (size_t)(m0 + lrow) * K + swcol;
  const u16* pB = Bw + (size_t)(n0 + lrow) * K + swcol;
  const size_t rstep = (size_t)32 * K;

  for (int kt = 0; kt < K; kt += 64) {
#pragma unroll
    for (int i = 0; i < 8; ++i)
      gload_lds16(pA + i * rstep + kt, &Als[(i * 32 + w * 8) * 64]);
#pragma unroll
    for (int i = 0; i < 4; ++i)
      gload_lds16(pB + i * rstep + kt, &Bls[(i * 32 + w * 8) * 64]);
    __syncthreads();
#pragma unroll
    for (int kk = 0; kk < 2; ++kk) {
      const int ch = ((kk * 4 + fg) ^ (fr & 7)) * 8;
      u16x8 b[4];
#pragma unroll
      for (int n = 0; n < 4; ++n)
        b[n] = *(const u16x8*)&Bls[(wc + n * 16 + fr) * 64 + ch];
#pragma unroll
      for (int mh = 0; mh < 2; ++mh) {
        u16x8 a[4];
#pragma unroll
        for (int m = 0; m < 4; ++m)
          a[m] = *(const u16x8*)&Als[(wr + (mh * 4 + m) * 16 + fr) * 64 + ch];
#pragma unroll
        for (int m = 0; m < 4; ++m)
#pragma unroll
          for (int n = 0; n < 4; ++n)
            acc[mh * 4 + m][n] = mfma16(a[m], b[n], acc[mh * 4 + m][n]);
      }
    }
    __syncthreads();
  }

  // epilogue
#pragma unroll
  for (int m = 0; m < 8; ++m) {
#pragma unroll
    for (int j = 0; j < 4; ++j) {
      int row = m0 + wr + m * 16 + fg * 4 + j;
      if (row >= M) continue;
#pragma unroll
      for (int n = 0; n < 4; ++n) {
        int col = n0 + wc + n * 16 + fr;
        float v = acc[m][n][j];
        if (Cf) Cf[(size_t)row * N + col] = v + bias[col];
        else    Cb[(size_t)row * N + col] = f2bf(v);
      }
    }
  }
}

// ======== fused attention: pool + stage1 + stage2 (one block per (b,h)) =====
__global__ __launch_bounds__(256) void attn_fused(
    const u16* __restrict__ qkv, u16* __restrict__ AO)
{
  __shared__ u16 Qp[64][72];     // pooled Q, this head's 64 dims
  __shared__ u16 Qd[64][72];     // Q_delta transposed: [dv][q]
  __shared__ u16 Kls[64][72];
  __shared__ u16 Vt[64][72];     // Vt[dv][key]
  __shared__ u16 Pls[4][16][72];

  int bh = blockIdx.x, b = bh >> 4, h = bh & 15;
  int t = threadIdx.x, lane = t & 63, w = t >> 6;
  int fr = lane & 15, fg = lane >> 4;

  // ---- pool ----
  {
    int pq = t >> 2, d0 = (t & 3) * 16;
    int py = pq >> 3, px = pq & 7;
    float s[16] = {};
#pragma unroll
    for (int dy = 0; dy < 3; ++dy)
#pragma unroll
      for (int dx = 0; dx < 3; ++dx) {
        int n = (py * 3 + dy) * 24 + px * 3 + dx;
        const u16* p = qkv + (size_t)(b * NN + n) * 3072 + h * DD + d0;
        u16x8 v0 = *(const u16x8*)p;
        u16x8 v1 = *(const u16x8*)(p + 8);
#pragma unroll
        for (int j = 0; j < 8; ++j) { s[j] += bf2f(v0[j]); s[8 + j] += bf2f(v1[j]); }
      }
    const float rinv = 1.f / 9.f;
    u16x8 o0, o1;
#pragma unroll
    for (int j = 0; j < 8; ++j) { o0[j] = f2bf(s[j] * rinv); o1[j] = f2bf(s[8 + j] * rinv); }
    *(u16x8*)&Qp[pq][d0] = o0;
    *(u16x8*)&Qp[pq][d0 + 8] = o1;
  }
  __syncthreads();

  // ---- stage 1 ----
  {
    u16x8 qf0 = *(const u16x8*)&Qp[w * 16 + fr][fg * 8];
    u16x8 qf1 = *(const u16x8*)&Qp[w * 16 + fr][32 + fg * 8];

    f32x4 o[4] = {};
    float rowm[4] = {-1e30f, -1e30f, -1e30f, -1e30f};
    float rowl[4] = {};

    for (int kt = 0; kt < 10; ++kt) {
#pragma unroll
      for (int i = 0; i < 2; ++i) {
        int g = t + i * 256;
        int key = g >> 3, cc = (g & 7) * 8;
        int n = kt * 64 + key;
        u16x8 kv = {}, vv = {};
        if (n < NN) {
          const u16* p = qkv + (size_t)(b * NN + n) * 3072 + h * DD + cc;
          kv = *(const u16x8*)(p + CC);
          vv = *(const u16x8*)(p + 2 * CC);
        }
        *(u16x8*)&Kls[key][cc] = kv;
#pragma unroll
        for (int j = 0; j < 8; ++j) Vt[cc + j][key] = vv[j];
      }
      __syncthreads();

      f32x4 s[4] = {};
#pragma unroll
      for (int kk = 0; kk < 2; ++kk) {
        u16x8 qf = kk ? qf1 : qf0;
#pragma unroll
        for (int n = 0; n < 4; ++n) {
          u16x8 kf = *(const u16x8*)&Kls[n * 16 + fr][kk * 32 + fg * 8];
          s[n] = mfma16(qf, kf, s[n]);
        }
      }
      float mx[4] = {-1e30f, -1e30f, -1e30f, -1e30f};
#pragma unroll
      for (int n = 0; n < 4; ++n) {
        int key = kt * 64 + n * 16 + fr;
#pragma unroll
        for (int j = 0; j < 4; ++j) {
          float v = s[n][j] * SCALE_;
          if (key >= NN) v = -1e30f;
          s[n][j] = v;
          mx[j] = fmaxf(mx[j], v);
        }
      }
      for (int d = 1; d < 16; d <<= 1) {
#pragma unroll
        for (int j = 0; j < 4; ++j) mx[j] = fmaxf(mx[j], __shfl_xor(mx[j], d));
      }
      float corr[4];
#pragma unroll
      for (int j = 0; j < 4; ++j) {
        float mn = fmaxf(rowm[j], mx[j]);
        corr[j] = __expf(rowm[j] - mn);
        rowm[j] = mn;
      }
      float rs[4] = {};
#pragma unroll
      for (int n = 0; n < 4; ++n)
#pragma unroll
        for (int j = 0; j < 4; ++j) {
          float p = __expf(s[n][j] - rowm[j]);
          s[n][j] = p;
          rs[j] += p;
        }
      for (int d = 1; d < 16; d <<= 1) {
#pragma unroll
        for (int j = 0; j < 4; ++j) rs[j] += __shfl_xor(rs[j], d);
      }
#pragma unroll
      for (int j = 0; j < 4; ++j) rowl[j] = rowl[j] * corr[j] + rs[j];
#pragma unroll
      for (int n = 0; n < 4; ++n)
#pragma unroll
        for (int j = 0; j < 4; ++j) o[n][j] *= corr[j];

#pragma unroll
      for (int n = 0; n < 4; ++n)
#pragma unroll
        for (int j = 0; j < 4; ++j)
          Pls[w][fg * 4 + j][n * 16 + fr] = f2bf(s[n][j]);
      __syncthreads();

#pragma unroll
      for (int kk = 0; kk < 2; ++kk) {
        u16x8 pf = *(const u16x8*)&Pls[w][fr][kk * 32 + fg * 8];
#pragma unroll
        for (int n = 0; n < 4; ++n) {
          u16x8 vf = *(const u16x8*)&Vt[n * 16 + fr][kk * 32 + fg * 8];
          o[n] = mfma16(pf, vf, o[n]);
        }
      }
      __syncthreads();
    }

#pragma unroll
    for (int n = 0; n < 4; ++n)
#pragma unroll
      for (int j = 0; j < 4; ++j)
        Qd[n * 16 + fr][w * 16 + fg * 4 + j] = f2bf(o[n][j] / rowl[j]);
  }
  __syncthreads();

  // ---- stage 2 ----
  u16x8 bq[2][4], dq[2][4];
#pragma unroll
  for (int kk = 0; kk < 2; ++kk)
#pragma unroll
    for (int n = 0; n < 4; ++n) {
      bq[kk][n] = *(const u16x8*)&Qp[n * 16 + fr][kk * 32 + fg * 8];
      dq[kk][n] = *(const u16x8*)&Qd[n * 16 + fr][kk * 32 + fg * 8];
    }

  for (int nt = 0; nt < 10; ++nt) {
    int n0 = nt * 64;
    int qrow = n0 + w * 16 + fr;
    int qc = qrow < NN ? qrow : NN - 1;
    const u16* Qb = qkv + (size_t)(b * NN + qc) * 3072 + h * DD;
    u16x8 a0 = *(const u16x8*)(Qb + fg * 8);
    u16x8 a1 = *(const u16x8*)(Qb + 32 + fg * 8);

    f32x4 s[4] = {};
#pragma unroll
    for (int n = 0; n < 4; ++n) {
      s[n] = mfma16(a0, bq[0][n], s[n]);
      s[n] = mfma16(a1, bq[1][n], s[n]);
    }
    float mx[4] = {-1e30f, -1e30f, -1e30f, -1e30f};
#pragma unroll
    for (int n = 0; n < 4; ++n)
#pragma unroll
      for (int j = 0; j < 4; ++j) {
        float v = s[n][j] * SCALE_;
        s[n][j] = v;
        mx[j] = fmaxf(mx[j], v);
      }
    for (int d = 1; d < 16; d <<= 1) {
#pragma unroll
      for (int j = 0; j < 4; ++j) mx[j] = fmaxf(mx[j], __shfl_xor(mx[j], d));
    }
    float rs[4] = {};
#pragma unroll
    for (int n = 0; n < 4; ++n)
#pragma unroll
      for (int j = 0; j < 4; ++j) {
        float p = __expf(s[n][j] - mx[j]);
        s[n][j] = p;
        rs[j] += p;
      }
    for (int d = 1; d < 16; d <<= 1) {
#pragma unroll
      for (int j = 0; j < 4; ++j) rs[j] += __shfl_xor(rs[j], d);
    }

#pragma unroll
    for (int n = 0; n < 4; ++n)
#pragma unroll
      for (int j = 0; j < 4; ++j)
        Pls[w][fg * 4 + j][n * 16 + fr] = f2bf(s[n][j]);
    __syncthreads();

    f32x4 of[4] = {};
#pragma unroll
    for (int kk = 0; kk < 2; ++kk) {
      u16x8 pf = *(const u16x8*)&Pls[w][fr][kk * 32 + fg * 8];
#pragma unroll
      for (int n = 0; n < 4; ++n)
        of[n] = mfma16(pf, dq[kk][n], of[n]);
    }

#pragma unroll
    for (int n = 0; n < 4; ++n)
#pragma unroll
      for (int j = 0; j < 4; ++j) {
        int orow = n0 + w * 16 + fg * 4 + j;
        if (orow < NN)
          AO[(size_t)(b * NN + orow) * CC + h * DD + n * 16 + fr] = f2bf(of[n][j] / rs[j]);
      }
    __syncthreads();
  }
}

// ---------------- launch ----------------
extern "C" void kernel_launch(void* const* d_in, const int* in_sizes, int n_in,
                              void* d_out, int out_size, void* d_ws, size_t ws_size,
                              hipStream_t stream) {
  const float* X     = (const float*)d_in[0];
  const float* Wqkv  = (const float*)d_in[1];
  const float* Wproj = (const float*)d_in[2];
  const float* bproj = (const float*)d_in[3];

  char* ws = (char*)d_ws;
  u16* Xb  = (u16*)(ws + 0);            // 18464*1024*2 = 37,814,272
  u16* Wqb = (u16*)(ws + 37814272);     // 3072*1024*2  =  6,291,456
  u16* Wpb = (u16*)(ws + 44105728);     // 1024*1024*2  =  2,097,152
  u16* qkv = (u16*)(ws + 46202880);     // 18464*3072*2 = 113,442,816
  u16* AO  = (u16*)(ws + 159645696);    // 18464*1024*2 = 37,814,272 (+slack)

  cvt3_kernel<<<2048, 256, 0, stream>>>(X, Wqkv, Wproj, Xb, Wqb, Wpb);

  // QKV: 256x128 tiles -> 73 x 24 = 1752 blocks
  gemm_w2<<<73 * 24, 256, 0, stream>>>(Xb, Wqb, qkv, nullptr, nullptr,
                                       MM, 3 * CC, CC, 73, 24);

  attn_fused<<<BB * HH, 256, 0, stream>>>(qkv, AO);

  // proj: 73 x 8 = 584 blocks
  gemm_w2<<<73 * 8, 256, 0, stream>>>(AO, Wpb, nullptr, (float*)d_out, bproj,
                                      MM, CC, CC, 73, 8);
}

// Round 11
// 295.266 us; speedup vs baseline: 1.5711x; 1.5711x over previous
//
#include <hip/hip_runtime.h>

typedef unsigned short u16;
typedef u16 u16x8 __attribute__((ext_vector_type(8)));
typedef u16 u16x4 __attribute__((ext_vector_type(4)));
typedef __bf16 bf16x8 __attribute__((ext_vector_type(8)));
typedef float f32x4 __attribute__((ext_vector_type(4)));

#define DEVI static __device__ __forceinline__

#define BB 32
#define NN 577
#define CC 1024
#define HH 16
#define DD 64
#define MM (BB * NN)   // 18464
#define SCALE_ 0.125f

DEVI u16 f2bf(float f) {
  union { float f; unsigned u; } v; v.f = f;
  unsigned r = v.u + 0x7FFFu + ((v.u >> 16) & 1u);
  return (u16)(r >> 16);
}
DEVI float bf2f(u16 b) {
  union { unsigned u; float f; } v; v.u = ((unsigned)b) << 16; return v.f;
}
DEVI f32x4 mfma16(u16x8 a, u16x8 b, f32x4 c) {
  return __builtin_amdgcn_mfma_f32_16x16x32_bf16(
      __builtin_bit_cast(bf16x8, a), __builtin_bit_cast(bf16x8, b), c, 0, 0, 0);
}
DEVI void gload_lds16(const u16* g, u16* l) {
  __builtin_amdgcn_global_load_lds(
      (const __attribute__((address_space(1))) void*)g,
      (__attribute__((address_space(3))) void*)l, 16, 0, 0);
}

// ---------------- fused fp32 -> bf16 convert (X, Wqkv, Wproj) ----------------
__global__ void cvt3_kernel(const float* __restrict__ X, const float* __restrict__ Wq,
                            const float* __restrict__ Wp, u16* __restrict__ Xb,
                            u16* __restrict__ Wqb, u16* __restrict__ Wpb) {
  const int nX = (MM * CC) / 4;
  const int nQ = (3 * CC * CC) / 4;
  const int nP = (CC * CC) / 4;
  const int total = nX + nQ + nP;
  int i = blockIdx.x * blockDim.x + threadIdx.x;
  int stride = gridDim.x * blockDim.x;
  for (; i < total; i += stride) {
    const float* in; u16* out; int k;
    if (i < nX)            { in = X;  out = Xb;  k = i; }
    else if (i < nX + nQ)  { in = Wq; out = Wqb; k = i - nX; }
    else                   { in = Wp; out = Wpb; k = i - nX - nQ; }
    float4 v = ((const float4*)in)[k];
    u16x4 o = { f2bf(v.x), f2bf(v.y), f2bf(v.z), f2bf(v.w) };
    ((u16x4*)out)[k] = o;
  }
}

// ---------------- GEMM (round-3 m97 structure + T2 swizzle) -----------------
// C[M,N] = A[M,K] * Bw[N,K]^T. bf16 out (Cb) or fp32+bias (Cf).
// Session fixed point: VGPR 80, 32KB LDS, ~2.4 blocks/CU, 774 TF on QKV shape.
__global__ __launch_bounds__(256) void gemm_bt2(
    const u16* __restrict__ A, const u16* __restrict__ Bw,
    u16* __restrict__ Cb, float* __restrict__ Cf, const float* __restrict__ bias,
    int M, int N, int K, int MT, int NT)
{
  __shared__ u16 Als[128 * 64];
  __shared__ u16 Bls[128 * 64];

  int nwg = MT * NT;
  int orig = blockIdx.x;
  int q = nwg >> 3, r = nwg & 7;
  int xcd = orig & 7, idx = orig >> 3;
  int wg = (xcd < r ? xcd * (q + 1) : r * (q + 1) + (xcd - r) * q) + idx;
  int mt = wg / NT, nt = wg % NT;

  const int t = threadIdx.x, lane = t & 63, w = t >> 6;
  const int wr = (w >> 1) * 64, wc = (w & 1) * 64;
  const int fr = lane & 15, fg = lane >> 4;
  const int m0 = mt * 128, n0 = nt * 128;
  f32x4 acc[4][4] = {};

  const int swcol = ((lane & 7) ^ ((lane >> 3) & 7)) * 8;
  const u16* pA[4];
  const u16* pB[4];
#pragma unroll
  for (int i = 0; i < 4; ++i) {
    int row = w * 32 + i * 8 + (lane >> 3);
    int ga = m0 + row; if (ga > M - 1) ga = M - 1;
    pA[i] = A + (size_t)ga * K + swcol;
    pB[i] = Bw + (size_t)(n0 + row) * K + swcol;
  }

  for (int kt = 0; kt < K; kt += 64) {
#pragma unroll
    for (int i = 0; i < 4; ++i) {
      int c = w * 4 + i;
      gload_lds16(pA[i] + kt, &Als[c * 512]);
      gload_lds16(pB[i] + kt, &Bls[c * 512]);
    }
    __syncthreads();
#pragma unroll
    for (int kk = 0; kk < 2; ++kk) {
      u16x8 af[4], bfr[4];
#pragma unroll
      for (int m = 0; m < 4; ++m) {
        int row = wr + m * 16 + fr;
        int ch = (kk * 4 + fg) ^ (fr & 7);
        af[m] = *(const u16x8*)&Als[row * 64 + ch * 8];
      }
#pragma unroll
      for (int n = 0; n < 4; ++n) {
        int row = wc + n * 16 + fr;
        int ch = (kk * 4 + fg) ^ (fr & 7);
        bfr[n] = *(const u16x8*)&Bls[row * 64 + ch * 8];
      }
#pragma unroll
      for (int m = 0; m < 4; ++m)
#pragma unroll
        for (int n = 0; n < 4; ++n)
          acc[m][n] = mfma16(af[m], bfr[n], acc[m][n]);
    }
    __syncthreads();
  }

#pragma unroll
  for (int m = 0; m < 4; ++m) {
#pragma unroll
    for (int j = 0; j < 4; ++j) {
      int row = m0 + wr + m * 16 + fg * 4 + j;
      if (row >= M) continue;
#pragma unroll
      for (int n = 0; n < 4; ++n) {
        int col = n0 + wc + n * 16 + fr;
        float v = acc[m][n][j];
        if (Cf) Cf[(size_t)row * N + col] = v + bias[col];
        else    Cb[(size_t)row * N + col] = f2bf(v);
      }
    }
  }
}

// ======== fused attention: pool + stage1 + stage2 (one block per (b,h)) =====
// Barrier audit vs round 8: Pls[w] is PER-WAVE scratch (written and read only
// by wave w; within-wave LDS ordering is compiler-enforced via lgkmcnt on the
// aliasing array) -> the post-P-write barrier in stage 1 (10x) and BOTH
// barriers in stage 2's nt loop (20x) are removed. Only block-wide K/V
// staging barriers remain.
__global__ __launch_bounds__(256) void attn_fused(
    const u16* __restrict__ qkv, u16* __restrict__ AO)
{
  __shared__ u16 Qp[64][72];     // pooled Q, this head's 64 dims
  __shared__ u16 Qd[64][72];     // Q_delta transposed: [dv][q]
  __shared__ u16 Kls[64][72];
  __shared__ u16 Vt[64][72];     // Vt[dv][key]
  __shared__ u16 Pls[4][16][72];

  int bh = blockIdx.x, b = bh >> 4, h = bh & 15;
  int t = threadIdx.x, lane = t & 63, w = t >> 6;
  int fr = lane & 15, fg = lane >> 4;

  // ---- pool ----
  {
    int pq = t >> 2, d0 = (t & 3) * 16;
    int py = pq >> 3, px = pq & 7;
    float s[16] = {};
#pragma unroll
    for (int dy = 0; dy < 3; ++dy)
#pragma unroll
      for (int dx = 0; dx < 3; ++dx) {
        int n = (py * 3 + dy) * 24 + px * 3 + dx;
        const u16* p = qkv + (size_t)(b * NN + n) * 3072 + h * DD + d0;
        u16x8 v0 = *(const u16x8*)p;
        u16x8 v1 = *(const u16x8*)(p + 8);
#pragma unroll
        for (int j = 0; j < 8; ++j) { s[j] += bf2f(v0[j]); s[8 + j] += bf2f(v1[j]); }
      }
    const float rinv = 1.f / 9.f;
    u16x8 o0, o1;
#pragma unroll
    for (int j = 0; j < 8; ++j) { o0[j] = f2bf(s[j] * rinv); o1[j] = f2bf(s[8 + j] * rinv); }
    *(u16x8*)&Qp[pq][d0] = o0;
    *(u16x8*)&Qp[pq][d0 + 8] = o1;
  }
  __syncthreads();

  // ---- stage 1 ----
  {
    u16x8 qf0 = *(const u16x8*)&Qp[w * 16 + fr][fg * 8];
    u16x8 qf1 = *(const u16x8*)&Qp[w * 16 + fr][32 + fg * 8];

    f32x4 o[4] = {};
    float rowm[4] = {-1e30f, -1e30f, -1e30f, -1e30f};
    float rowl[4] = {};

    for (int kt = 0; kt < 10; ++kt) {
#pragma unroll
      for (int i = 0; i < 2; ++i) {
        int g = t + i * 256;
        int key = g >> 3, cc = (g & 7) * 8;
        int n = kt * 64 + key;
        u16x8 kv = {}, vv = {};
        if (n < NN) {
          const u16* p = qkv + (size_t)(b * NN + n) * 3072 + h * DD + cc;
          kv = *(const u16x8*)(p + CC);
          vv = *(const u16x8*)(p + 2 * CC);
        }
        *(u16x8*)&Kls[key][cc] = kv;
#pragma unroll
        for (int j = 0; j < 8; ++j) Vt[cc + j][key] = vv[j];
      }
      __syncthreads();   // block-wide: K/V ready

      f32x4 s[4] = {};
#pragma unroll
      for (int kk = 0; kk < 2; ++kk) {
        u16x8 qf = kk ? qf1 : qf0;
#pragma unroll
        for (int n = 0; n < 4; ++n) {
          u16x8 kf = *(const u16x8*)&Kls[n * 16 + fr][kk * 32 + fg * 8];
          s[n] = mfma16(qf, kf, s[n]);
        }
      }
      float mx[4] = {-1e30f, -1e30f, -1e30f, -1e30f};
#pragma unroll
      for (int n = 0; n < 4; ++n) {
        int key = kt * 64 + n * 16 + fr;
#pragma unroll
        for (int j = 0; j < 4; ++j) {
          float v = s[n][j] * SCALE_;
          if (key >= NN) v = -1e30f;
          s[n][j] = v;
          mx[j] = fmaxf(mx[j], v);
        }
      }
      for (int d = 1; d < 16; d <<= 1) {
#pragma unroll
        for (int j = 0; j < 4; ++j) mx[j] = fmaxf(mx[j], __shfl_xor(mx[j], d));
      }
      float corr[4];
#pragma unroll
      for (int j = 0; j < 4; ++j) {
        float mn = fmaxf(rowm[j], mx[j]);
        corr[j] = __expf(rowm[j] - mn);
        rowm[j] = mn;
      }
      float rs[4] = {};
#pragma unroll
      for (int n = 0; n < 4; ++n)
#pragma unroll
        for (int j = 0; j < 4; ++j) {
          float p = __expf(s[n][j] - rowm[j]);
          s[n][j] = p;
          rs[j] += p;
        }
      for (int d = 1; d < 16; d <<= 1) {
#pragma unroll
        for (int j = 0; j < 4; ++j) rs[j] += __shfl_xor(rs[j], d);
      }
#pragma unroll
      for (int j = 0; j < 4; ++j) rowl[j] = rowl[j] * corr[j] + rs[j];
#pragma unroll
      for (int n = 0; n < 4; ++n)
#pragma unroll
        for (int j = 0; j < 4; ++j) o[n][j] *= corr[j];

      // P -> per-wave LDS region; no block barrier needed (same-wave RAW)
#pragma unroll
      for (int n = 0; n < 4; ++n)
#pragma unroll
        for (int j = 0; j < 4; ++j)
          Pls[w][fg * 4 + j][n * 16 + fr] = f2bf(s[n][j]);

#pragma unroll
      for (int kk = 0; kk < 2; ++kk) {
        u16x8 pf = *(const u16x8*)&Pls[w][fr][kk * 32 + fg * 8];
#pragma unroll
        for (int n = 0; n < 4; ++n) {
          u16x8 vf = *(const u16x8*)&Vt[n * 16 + fr][kk * 32 + fg * 8];
          o[n] = mfma16(pf, vf, o[n]);
        }
      }
      __syncthreads();   // block-wide: protect Kls/Vt for next kt's staging
    }

#pragma unroll
    for (int n = 0; n < 4; ++n)
#pragma unroll
      for (int j = 0; j < 4; ++j)
        Qd[n * 16 + fr][w * 16 + fg * 4 + j] = f2bf(o[n][j] / rowl[j]);
  }
  __syncthreads();   // block-wide: Qd complete before stage-2 fragment reads

  // ---- stage 2: barrier-free after fragment hoist (all per-wave work) ----
  u16x8 bq[2][4], dq[2][4];
#pragma unroll
  for (int kk = 0; kk < 2; ++kk)
#pragma unroll
    for (int n = 0; n < 4; ++n) {
      bq[kk][n] = *(const u16x8*)&Qp[n * 16 + fr][kk * 32 + fg * 8];
      dq[kk][n] = *(const u16x8*)&Qd[n * 16 + fr][kk * 32 + fg * 8];
    }

  for (int nt = 0; nt < 10; ++nt) {
    int n0 = nt * 64;
    int qrow = n0 + w * 16 + fr;
    int qc = qrow < NN ? qrow : NN - 1;
    const u16* Qb = qkv + (size_t)(b * NN + qc) * 3072 + h * DD;
    u16x8 a0 = *(const u16x8*)(Qb + fg * 8);
    u16x8 a1 = *(const u16x8*)(Qb + 32 + fg * 8);

    f32x4 s[4] = {};
#pragma unroll
    for (int n = 0; n < 4; ++n) {
      s[n] = mfma16(a0, bq[0][n], s[n]);
      s[n] = mfma16(a1, bq[1][n], s[n]);
    }
    float mx[4] = {-1e30f, -1e30f, -1e30f, -1e30f};
#pragma unroll
    for (int n = 0; n < 4; ++n)
#pragma unroll
      for (int j = 0; j < 4; ++j) {
        float v = s[n][j] * SCALE_;
        s[n][j] = v;
        mx[j] = fmaxf(mx[j], v);
      }
    for (int d = 1; d < 16; d <<= 1) {
#pragma unroll
      for (int j = 0; j < 4; ++j) mx[j] = fmaxf(mx[j], __shfl_xor(mx[j], d));
    }
    float rs[4] = {};
#pragma unroll
    for (int n = 0; n < 4; ++n)
#pragma unroll
      for (int j = 0; j < 4; ++j) {
        float p = __expf(s[n][j] - mx[j]);
        s[n][j] = p;
        rs[j] += p;
      }
    for (int d = 1; d < 16; d <<= 1) {
#pragma unroll
      for (int j = 0; j < 4; ++j) rs[j] += __shfl_xor(rs[j], d);
    }

    // P -> per-wave LDS region; same-wave RAW only — no barriers in this loop
#pragma unroll
    for (int n = 0; n < 4; ++n)
#pragma unroll
      for (int j = 0; j < 4; ++j)
        Pls[w][fg * 4 + j][n * 16 + fr] = f2bf(s[n][j]);

    f32x4 of[4] = {};
#pragma unroll
    for (int kk = 0; kk < 2; ++kk) {
      u16x8 pf = *(const u16x8*)&Pls[w][fr][kk * 32 + fg * 8];
#pragma unroll
      for (int n = 0; n < 4; ++n)
        of[n] = mfma16(pf, dq[kk][n], of[n]);
    }

#pragma unroll
    for (int n = 0; n < 4; ++n)
#pragma unroll
      for (int j = 0; j < 4; ++j) {
        int orow = n0 + w * 16 + fg * 4 + j;
        if (orow < NN)
          AO[(size_t)(b * NN + orow) * CC + h * DD + n * 16 + fr] = f2bf(of[n][j] / rs[j]);
      }
  }
}

// ---------------- launch ----------------
extern "C" void kernel_launch(void* const* d_in, const int* in_sizes, int n_in,
                              void* d_out, int out_size, void* d_ws, size_t ws_size,
                              hipStream_t stream) {
  const float* X     = (const float*)d_in[0];
  const float* Wqkv  = (const float*)d_in[1];
  const float* Wproj = (const float*)d_in[2];
  const float* bproj = (const float*)d_in[3];

  char* ws = (char*)d_ws;
  u16* Xb  = (u16*)(ws + 0);            // 18464*1024*2 = 37,814,272
  u16* Wqb = (u16*)(ws + 37814272);     // 3072*1024*2  =  6,291,456
  u16* Wpb = (u16*)(ws + 44105728);     // 1024*1024*2  =  2,097,152
  u16* qkv = (u16*)(ws + 46202880);     // 18464*3072*2 = 113,442,816
  u16* AO  = (u16*)(ws + 159645696);    // 18464*1024*2 = 37,814,272

  cvt3_kernel<<<2048, 256, 0, stream>>>(X, Wqkv, Wproj, Xb, Wqb, Wpb);

  gemm_bt2<<<145 * 24, 256, 0, stream>>>(Xb, Wqb, qkv, nullptr, nullptr,
                                         MM, 3 * CC, CC, 145, 24);

  attn_fused<<<BB * HH, 256, 0, stream>>>(qkv, AO);

  gemm_bt2<<<145 * 8, 256, 0, stream>>>(AO, Wpb, nullptr, (float*)d_out, bproj,
                                        MM, CC, CC, 145, 8);
}

// Round 12
// 285.125 us; speedup vs baseline: 1.6270x; 1.0356x over previous
//
#include <hip/hip_runtime.h>

typedef unsigned short u16;
typedef u16 u16x8 __attribute__((ext_vector_type(8)));
typedef u16 u16x4 __attribute__((ext_vector_type(4)));
typedef __bf16 bf16x8 __attribute__((ext_vector_type(8)));
typedef float f32x4 __attribute__((ext_vector_type(4)));

#define DEVI static __device__ __forceinline__

#define BB 32
#define NN 577
#define CC 1024
#define HH 16
#define DD 64
#define MM (BB * NN)   // 18464
#define SCALE_ 0.125f

DEVI u16 f2bf(float f) {
  union { float f; unsigned u; } v; v.f = f;
  unsigned r = v.u + 0x7FFFu + ((v.u >> 16) & 1u);
  return (u16)(r >> 16);
}
DEVI float bf2f(u16 b) {
  union { unsigned u; float f; } v; v.u = ((unsigned)b) << 16; return v.f;
}
DEVI f32x4 mfma16(u16x8 a, u16x8 b, f32x4 c) {
  return __builtin_amdgcn_mfma_f32_16x16x32_bf16(
      __builtin_bit_cast(bf16x8, a), __builtin_bit_cast(bf16x8, b), c, 0, 0, 0);
}
DEVI void gload_lds16(const u16* g, u16* l) {
  __builtin_amdgcn_global_load_lds(
      (const __attribute__((address_space(1))) void*)g,
      (__attribute__((address_space(3))) void*)l, 16, 0, 0);
}
DEVI void fencec() { asm volatile("" ::: "memory"); }
DEVI void lbar() { fencec(); __builtin_amdgcn_s_barrier(); fencec(); }

// ---------------- fused fp32 -> bf16 convert (X, Wqkv, Wproj) ----------------
__global__ void cvt3_kernel(const float* __restrict__ X, const float* __restrict__ Wq,
                            const float* __restrict__ Wp, u16* __restrict__ Xb,
                            u16* __restrict__ Wqb, u16* __restrict__ Wpb) {
  const int nX = (MM * CC) / 4;
  const int nQ = (3 * CC * CC) / 4;
  const int nP = (CC * CC) / 4;
  const int total = nX + nQ + nP;
  int i = blockIdx.x * blockDim.x + threadIdx.x;
  int stride = gridDim.x * blockDim.x;
  for (; i < total; i += stride) {
    const float* in; u16* out; int k;
    if (i < nX)            { in = X;  out = Xb;  k = i; }
    else if (i < nX + nQ)  { in = Wq; out = Wqb; k = i - nX; }
    else                   { in = Wp; out = Wpb; k = i - nX - nQ; }
    float4 v = ((const float4*)in)[k];
    u16x4 o = { f2bf(v.x), f2bf(v.y), f2bf(v.z), f2bf(v.w) };
    ((u16x4*)out)[k] = o;
  }
}

// ======== 8-phase staggered GEMM: 256x256, BK=64, 8 waves, 2-dbuf ===========
// C[M,N] = A[M,K]*Bw[N,K]^T, bf16 out. Phase/quadrant schedule per K-tile T:
//  p0: read aL(8)+bL(4); stage B-h0(T+1); bar; MFMA Q0(aLxbL); bar
//  p1: read aH(8);       stage B-h1(T+1); bar; MFMA Q1(aHxbL); bar
//  p2: read bH(4);       stage A-h0(T+2); bar; MFMA Q2(aLxbH); bar
//  p3:                   stage A-h1(T+2); bar; MFMA Q3(aHxbH); vmcnt(4); bar
// Staggered prefetch: B staged 2-3 phases ahead (L2-hot weights), A staged
// 6 phases ahead (HBM stream). ONE counted vmcnt(4) per K-tile (never 0 in
// steady state). Ledger: at T's p3 wait, outstanding = B(T+1):4 + A(T+2):4;
// vmcnt(4) retires B(T+1) [and older A(T+1)], leaves A(T+2) in flight.
// WAR: any staged region's last reader finished >=2 barriers earlier.
__global__ __launch_bounds__(512, 1) void gemm_8p(
    const u16* __restrict__ A, const u16* __restrict__ Bw,
    u16* __restrict__ Cb, int M, int N, int K, int MT, int NT)
{
  __shared__ u16 Als[2][16384];   // [buf][half*8192 + ...] 64 KB
  __shared__ u16 Bls[2][16384];   // 64 KB

  // bijective XCD swizzle (m204)
  int nwg = MT * NT;
  int orig = blockIdx.x;
  int q = nwg >> 3, r = nwg & 7;
  int xcd = orig & 7, idx = orig >> 3;
  int wg = (xcd < r ? xcd * (q + 1) : r * (q + 1) + (xcd - r) * q) + idx;
  int mt = wg / NT, nt = wg % NT;

  const int t = threadIdx.x, lane = t & 63, w = t >> 6;
  const int wr2 = w >> 2, wc2 = w & 3;      // 2(M) x 4(N) wave grid
  const int fr = lane & 15, fg = lane >> 4;
  const int m0 = mt * 256, n0 = nt * 256;

  f32x4 acc[8][4] = {};

  // staging pointers: instr (w,j) of half h covers rows h*128+(w*2+j)*8+(lane>>3),
  // 16B chunk (lane&7), source col pre-swizzled by row&7 (row&7 == lane>>3 here).
  const int swcol = ((lane & 7) ^ ((lane >> 3) & 7)) * 8;
  const u16* pA[2][2];
  const u16* pB[2][2];
#pragma unroll
  for (int h = 0; h < 2; ++h)
#pragma unroll
    for (int j = 0; j < 2; ++j) {
      int row = h * 128 + (w * 2 + j) * 8 + (lane >> 3);
      int ga = m0 + row; if (ga > M - 1) ga = M - 1;
      pA[h][j] = A + (size_t)ga * K + swcol;
      pB[h][j] = Bw + (size_t)(n0 + row) * K + swcol;   // N % 256 == 0
    }
  const int lofs = (w * 2) * 512;   // wave-uniform LDS elem offset (j adds 512)

  auto stageA = [&](int tile, int h, int buf) {
    const int kc = tile << 6;
    gload_lds16(pA[h][0] + kc, &Als[buf][h * 8192 + lofs]);
    gload_lds16(pA[h][1] + kc, &Als[buf][h * 8192 + lofs + 512]);
  };
  auto stageB = [&](int tile, int h, int buf) {
    const int kc = tile << 6;
    gload_lds16(pB[h][0] + kc, &Bls[buf][h * 8192 + lofs]);
    gload_lds16(pB[h][1] + kc, &Bls[buf][h * 8192 + lofs + 512]);
  };

  // fragment addresses (swizzled chunk: ch = (kk*4+fg)^(fr&7))
  const int chk[2] = { ((0 * 4 + fg) ^ (fr & 7)) * 8, ((1 * 4 + fg) ^ (fr & 7)) * 8 };
  const int arow = wr2 * 128 + fr;   // + m*16
  const int brow = wc2 * 64 + fr;    // + n*16

  const int nkt = K >> 6;   // 16

  // prologue: tile0 complete + A-halves of tile1 in flight
  stageA(0, 0, 0); stageA(0, 1, 0);
  stageB(0, 0, 0); stageB(0, 1, 0);
  stageA(1, 0, 1); stageA(1, 1, 1);
  asm volatile("s_waitcnt vmcnt(4)" ::: "memory");   // tile0's 8 loads landed
  lbar();

  u16x8 aL[4][2], aH[4][2], bL[2][2], bH[2][2];

  for (int T = 0; T < nkt; ++T) {
    const int cur = T & 1, nxt = cur ^ 1;
    const u16* Ac = &Als[cur][0];
    const u16* Bc = &Bls[cur][0];
    const bool s1 = (T + 1 < nkt), s2 = (T + 2 < nkt);

    // ---- p0: aL + bL reads; stage B-h0(T+1); MFMA Q0 ----
#pragma unroll
    for (int m = 0; m < 4; ++m)
#pragma unroll
      for (int kk = 0; kk < 2; ++kk)
        aL[m][kk] = *(const u16x8*)&Ac[(arow + m * 16) * 64 + chk[kk]];
#pragma unroll
    for (int n = 0; n < 2; ++n)
#pragma unroll
      for (int kk = 0; kk < 2; ++kk)
        bL[n][kk] = *(const u16x8*)&Bc[(brow + n * 16) * 64 + chk[kk]];
    if (s1) stageB(T + 1, 0, nxt);
    lbar();
    __builtin_amdgcn_s_setprio(1);
#pragma unroll
    for (int m = 0; m < 4; ++m)
#pragma unroll
      for (int n = 0; n < 2; ++n)
#pragma unroll
        for (int kk = 0; kk < 2; ++kk)
          acc[m][n] = mfma16(aL[m][kk], bL[n][kk], acc[m][n]);
    __builtin_amdgcn_s_setprio(0);
    lbar();

    // ---- p1: aH reads; stage B-h1(T+1); MFMA Q1 ----
#pragma unroll
    for (int m = 0; m < 4; ++m)
#pragma unroll
      for (int kk = 0; kk < 2; ++kk)
        aH[m][kk] = *(const u16x8*)&Ac[(arow + (m + 4) * 16) * 64 + chk[kk]];
    if (s1) stageB(T + 1, 1, nxt);
    lbar();
    __builtin_amdgcn_s_setprio(1);
#pragma unroll
    for (int m = 0; m < 4; ++m)
#pragma unroll
      for (int n = 0; n < 2; ++n)
#pragma unroll
        for (int kk = 0; kk < 2; ++kk)
          acc[m + 4][n] = mfma16(aH[m][kk], bL[n][kk], acc[m + 4][n]);
    __builtin_amdgcn_s_setprio(0);
    lbar();

    // ---- p2: bH reads; stage A-h0(T+2); MFMA Q2 ----
#pragma unroll
    for (int n = 0; n < 2; ++n)
#pragma unroll
      for (int kk = 0; kk < 2; ++kk)
        bH[n][kk] = *(const u16x8*)&Bc[(brow + (n + 2) * 16) * 64 + chk[kk]];
    if (s2) stageA(T + 2, 0, cur);
    lbar();
    __builtin_amdgcn_s_setprio(1);
#pragma unroll
    for (int m = 0; m < 4; ++m)
#pragma unroll
      for (int n = 0; n < 2; ++n)
#pragma unroll
        for (int kk = 0; kk < 2; ++kk)
          acc[m][n + 2] = mfma16(aL[m][kk], bH[n][kk], acc[m][n + 2]);
    __builtin_amdgcn_s_setprio(0);
    lbar();

    // ---- p3: stage A-h1(T+2); MFMA Q3; counted vmcnt ----
    if (s2) stageA(T + 2, 1, cur);
    lbar();
    __builtin_amdgcn_s_setprio(1);
#pragma unroll
    for (int m = 0; m < 4; ++m)
#pragma unroll
      for (int n = 0; n < 2; ++n)
#pragma unroll
        for (int kk = 0; kk < 2; ++kk)
          acc[m + 4][n + 2] = mfma16(aH[m][kk], bH[n][kk], acc[m + 4][n + 2]);
    __builtin_amdgcn_s_setprio(0);
    if (s2) asm volatile("s_waitcnt vmcnt(4)" ::: "memory");   // T+1 ready
    else    asm volatile("s_waitcnt vmcnt(0)" ::: "memory");   // tail drain
    lbar();
  }

  // epilogue
#pragma unroll
  for (int m = 0; m < 8; ++m) {
#pragma unroll
    for (int j = 0; j < 4; ++j) {
      int row = m0 + wr2 * 128 + m * 16 + fg * 4 + j;
      if (row >= M) continue;
#pragma unroll
      for (int n = 0; n < 4; ++n) {
        int col = n0 + wc2 * 64 + n * 16 + fr;
        Cb[(size_t)row * N + col] = f2bf(acc[m][n][j]);
      }
    }
  }
}

// ---------------- GEMM (round-3 m97 structure + T2 swizzle) -----------------
__global__ __launch_bounds__(256) void gemm_bt2(
    const u16* __restrict__ A, const u16* __restrict__ Bw,
    u16* __restrict__ Cb, float* __restrict__ Cf, const float* __restrict__ bias,
    int M, int N, int K, int MT, int NT)
{
  __shared__ u16 Als[128 * 64];
  __shared__ u16 Bls[128 * 64];

  int nwg = MT * NT;
  int orig = blockIdx.x;
  int q = nwg >> 3, r = nwg & 7;
  int xcd = orig & 7, idx = orig >> 3;
  int wg = (xcd < r ? xcd * (q + 1) : r * (q + 1) + (xcd - r) * q) + idx;
  int mt = wg / NT, nt = wg % NT;

  const int t = threadIdx.x, lane = t & 63, w = t >> 6;
  const int wr = (w >> 1) * 64, wc = (w & 1) * 64;
  const int fr = lane & 15, fg = lane >> 4;
  const int m0 = mt * 128, n0 = nt * 128;
  f32x4 acc[4][4] = {};

  const int swcol = ((lane & 7) ^ ((lane >> 3) & 7)) * 8;
  const u16* pA[4];
  const u16* pB[4];
#pragma unroll
  for (int i = 0; i < 4; ++i) {
    int row = w * 32 + i * 8 + (lane >> 3);
    int ga = m0 + row; if (ga > M - 1) ga = M - 1;
    pA[i] = A + (size_t)ga * K + swcol;
    pB[i] = Bw + (size_t)(n0 + row) * K + swcol;
  }

  for (int kt = 0; kt < K; kt += 64) {
#pragma unroll
    for (int i = 0; i < 4; ++i) {
      int c = w * 4 + i;
      gload_lds16(pA[i] + kt, &Als[c * 512]);
      gload_lds16(pB[i] + kt, &Bls[c * 512]);
    }
    __syncthreads();
#pragma unroll
    for (int kk = 0; kk < 2; ++kk) {
      u16x8 af[4], bfr[4];
#pragma unroll
      for (int m = 0; m < 4; ++m) {
        int row = wr + m * 16 + fr;
        int ch = (kk * 4 + fg) ^ (fr & 7);
        af[m] = *(const u16x8*)&Als[row * 64 + ch * 8];
      }
#pragma unroll
      for (int n = 0; n < 4; ++n) {
        int row = wc + n * 16 + fr;
        int ch = (kk * 4 + fg) ^ (fr & 7);
        bfr[n] = *(const u16x8*)&Bls[row * 64 + ch * 8];
      }
#pragma unroll
      for (int m = 0; m < 4; ++m)
#pragma unroll
        for (int n = 0; n < 4; ++n)
          acc[m][n] = mfma16(af[m], bfr[n], acc[m][n]);
    }
    __syncthreads();
  }

#pragma unroll
  for (int m = 0; m < 4; ++m) {
#pragma unroll
    for (int j = 0; j < 4; ++j) {
      int row = m0 + wr + m * 16 + fg * 4 + j;
      if (row >= M) continue;
#pragma unroll
      for (int n = 0; n < 4; ++n) {
        int col = n0 + wc + n * 16 + fr;
        float v = acc[m][n][j];
        if (Cf) Cf[(size_t)row * N + col] = v + bias[col];
        else    Cb[(size_t)row * N + col] = f2bf(v);
      }
    }
  }
}

// ======== fused attention: pool + stage1 + stage2 (one block per (b,h)) =====
__global__ __launch_bounds__(256) void attn_fused(
    const u16* __restrict__ qkv, u16* __restrict__ AO)
{
  __shared__ u16 Qp[64][72];
  __shared__ u16 Qd[64][72];
  __shared__ u16 Kls[64][72];
  __shared__ u16 Vt[64][72];
  __shared__ u16 Pls[4][16][72];

  int bh = blockIdx.x, b = bh >> 4, h = bh & 15;
  int t = threadIdx.x, lane = t & 63, w = t >> 6;
  int fr = lane & 15, fg = lane >> 4;

  // ---- pool ----
  {
    int pq = t >> 2, d0 = (t & 3) * 16;
    int py = pq >> 3, px = pq & 7;
    float s[16] = {};
#pragma unroll
    for (int dy = 0; dy < 3; ++dy)
#pragma unroll
      for (int dx = 0; dx < 3; ++dx) {
        int n = (py * 3 + dy) * 24 + px * 3 + dx;
        const u16* p = qkv + (size_t)(b * NN + n) * 3072 + h * DD + d0;
        u16x8 v0 = *(const u16x8*)p;
        u16x8 v1 = *(const u16x8*)(p + 8);
#pragma unroll
        for (int j = 0; j < 8; ++j) { s[j] += bf2f(v0[j]); s[8 + j] += bf2f(v1[j]); }
      }
    const float rinv = 1.f / 9.f;
    u16x8 o0, o1;
#pragma unroll
    for (int j = 0; j < 8; ++j) { o0[j] = f2bf(s[j] * rinv); o1[j] = f2bf(s[8 + j] * rinv); }
    *(u16x8*)&Qp[pq][d0] = o0;
    *(u16x8*)&Qp[pq][d0 + 8] = o1;
  }
  __syncthreads();

  // ---- stage 1 ----
  {
    u16x8 qf0 = *(const u16x8*)&Qp[w * 16 + fr][fg * 8];
    u16x8 qf1 = *(const u16x8*)&Qp[w * 16 + fr][32 + fg * 8];

    f32x4 o[4] = {};
    float rowm[4] = {-1e30f, -1e30f, -1e30f, -1e30f};
    float rowl[4] = {};

    for (int kt = 0; kt < 10; ++kt) {
#pragma unroll
      for (int i = 0; i < 2; ++i) {
        int g = t + i * 256;
        int key = g >> 3, cc = (g & 7) * 8;
        int n = kt * 64 + key;
        u16x8 kv = {}, vv = {};
        if (n < NN) {
          const u16* p = qkv + (size_t)(b * NN + n) * 3072 + h * DD + cc;
          kv = *(const u16x8*)(p + CC);
          vv = *(const u16x8*)(p + 2 * CC);
        }
        *(u16x8*)&Kls[key][cc] = kv;
#pragma unroll
        for (int j = 0; j < 8; ++j) Vt[cc + j][key] = vv[j];
      }
      __syncthreads();

      f32x4 s[4] = {};
#pragma unroll
      for (int kk = 0; kk < 2; ++kk) {
        u16x8 qf = kk ? qf1 : qf0;
#pragma unroll
        for (int n = 0; n < 4; ++n) {
          u16x8 kf = *(const u16x8*)&Kls[n * 16 + fr][kk * 32 + fg * 8];
          s[n] = mfma16(qf, kf, s[n]);
        }
      }
      float mx[4] = {-1e30f, -1e30f, -1e30f, -1e30f};
#pragma unroll
      for (int n = 0; n < 4; ++n) {
        int key = kt * 64 + n * 16 + fr;
#pragma unroll
        for (int j = 0; j < 4; ++j) {
          float v = s[n][j] * SCALE_;
          if (key >= NN) v = -1e30f;
          s[n][j] = v;
          mx[j] = fmaxf(mx[j], v);
        }
      }
      for (int d = 1; d < 16; d <<= 1) {
#pragma unroll
        for (int j = 0; j < 4; ++j) mx[j] = fmaxf(mx[j], __shfl_xor(mx[j], d));
      }
      float corr[4];
#pragma unroll
      for (int j = 0; j < 4; ++j) {
        float mn = fmaxf(rowm[j], mx[j]);
        corr[j] = __expf(rowm[j] - mn);
        rowm[j] = mn;
      }
      float rs[4] = {};
#pragma unroll
      for (int n = 0; n < 4; ++n)
#pragma unroll
        for (int j = 0; j < 4; ++j) {
          float p = __expf(s[n][j] - rowm[j]);
          s[n][j] = p;
          rs[j] += p;
        }
      for (int d = 1; d < 16; d <<= 1) {
#pragma unroll
        for (int j = 0; j < 4; ++j) rs[j] += __shfl_xor(rs[j], d);
      }
#pragma unroll
      for (int j = 0; j < 4; ++j) rowl[j] = rowl[j] * corr[j] + rs[j];
#pragma unroll
      for (int n = 0; n < 4; ++n)
#pragma unroll
        for (int j = 0; j < 4; ++j) o[n][j] *= corr[j];

#pragma unroll
      for (int n = 0; n < 4; ++n)
#pragma unroll
        for (int j = 0; j < 4; ++j)
          Pls[w][fg * 4 + j][n * 16 + fr] = f2bf(s[n][j]);

#pragma unroll
      for (int kk = 0; kk < 2; ++kk) {
        u16x8 pf = *(const u16x8*)&Pls[w][fr][kk * 32 + fg * 8];
#pragma unroll
        for (int n = 0; n < 4; ++n) {
          u16x8 vf = *(const u16x8*)&Vt[n * 16 + fr][kk * 32 + fg * 8];
          o[n] = mfma16(pf, vf, o[n]);
        }
      }
      __syncthreads();
    }

#pragma unroll
    for (int n = 0; n < 4; ++n)
#pragma unroll
      for (int j = 0; j < 4; ++j)
        Qd[n * 16 + fr][w * 16 + fg * 4 + j] = f2bf(o[n][j] / rowl[j]);
  }
  __syncthreads();

  // ---- stage 2 ----
  u16x8 bq[2][4], dq[2][4];
#pragma unroll
  for (int kk = 0; kk < 2; ++kk)
#pragma unroll
    for (int n = 0; n < 4; ++n) {
      bq[kk][n] = *(const u16x8*)&Qp[n * 16 + fr][kk * 32 + fg * 8];
      dq[kk][n] = *(const u16x8*)&Qd[n * 16 + fr][kk * 32 + fg * 8];
    }

  for (int nt = 0; nt < 10; ++nt) {
    int n0 = nt * 64;
    int qrow = n0 + w * 16 + fr;
    int qc = qrow < NN ? qrow : NN - 1;
    const u16* Qb = qkv + (size_t)(b * NN + qc) * 3072 + h * DD;
    u16x8 a0 = *(const u16x8*)(Qb + fg * 8);
    u16x8 a1 = *(const u16x8*)(Qb + 32 + fg * 8);

    f32x4 s[4] = {};
#pragma unroll
    for (int n = 0; n < 4; ++n) {
      s[n] = mfma16(a0, bq[0][n], s[n]);
      s[n] = mfma16(a1, bq[1][n], s[n]);
    }
    float mx[4] = {-1e30f, -1e30f, -1e30f, -1e30f};
#pragma unroll
    for (int n = 0; n < 4; ++n)
#pragma unroll
      for (int j = 0; j < 4; ++j) {
        float v = s[n][j] * SCALE_;
        s[n][j] = v;
        mx[j] = fmaxf(mx[j], v);
      }
    for (int d = 1; d < 16; d <<= 1) {
#pragma unroll
      for (int j = 0; j < 4; ++j) mx[j] = fmaxf(mx[j], __shfl_xor(mx[j], d));
    }
    float rs[4] = {};
#pragma unroll
    for (int n = 0; n < 4; ++n)
#pragma unroll
      for (int j = 0; j < 4; ++j) {
        float p = __expf(s[n][j] - mx[j]);
        s[n][j] = p;
        rs[j] += p;
      }
    for (int d = 1; d < 16; d <<= 1) {
#pragma unroll
      for (int j = 0; j < 4; ++j) rs[j] += __shfl_xor(rs[j], d);
    }

#pragma unroll
    for (int n = 0; n < 4; ++n)
#pragma unroll
      for (int j = 0; j < 4; ++j)
        Pls[w][fg * 4 + j][n * 16 + fr] = f2bf(s[n][j]);

    f32x4 of[4] = {};
#pragma unroll
    for (int kk = 0; kk < 2; ++kk) {
      u16x8 pf = *(const u16x8*)&Pls[w][fr][kk * 32 + fg * 8];
#pragma unroll
      for (int n = 0; n < 4; ++n)
        of[n] = mfma16(pf, dq[kk][n], of[n]);
    }

#pragma unroll
    for (int n = 0; n < 4; ++n)
#pragma unroll
      for (int j = 0; j < 4; ++j) {
        int orow = n0 + w * 16 + fg * 4 + j;
        if (orow < NN)
          AO[(size_t)(b * NN + orow) * CC + h * DD + n * 16 + fr] = f2bf(of[n][j] / rs[j]);
      }
  }
}

// ---------------- launch ----------------
extern "C" void kernel_launch(void* const* d_in, const int* in_sizes, int n_in,
                              void* d_out, int out_size, void* d_ws, size_t ws_size,
                              hipStream_t stream) {
  const float* X     = (const float*)d_in[0];
  const float* Wqkv  = (const float*)d_in[1];
  const float* Wproj = (const float*)d_in[2];
  const float* bproj = (const float*)d_in[3];

  char* ws = (char*)d_ws;
  u16* Xb  = (u16*)(ws + 0);            // 18464*1024*2 = 37,814,272
  u16* Wqb = (u16*)(ws + 37814272);     // 3072*1024*2  =  6,291,456
  u16* Wpb = (u16*)(ws + 44105728);     // 1024*1024*2  =  2,097,152
  u16* qkv = (u16*)(ws + 46202880);     // 18464*3072*2 = 113,442,816
  u16* AO  = (u16*)(ws + 159645696);    // 18464*1024*2 = 37,814,272

  cvt3_kernel<<<2048, 256, 0, stream>>>(X, Wqkv, Wproj, Xb, Wqb, Wpb);

  // QKV: 8-phase staggered 256x256 (73 x 12 = 876 blocks)
  gemm_8p<<<73 * 12, 512, 0, stream>>>(Xb, Wqb, qkv, MM, 3 * CC, CC, 73, 12);

  attn_fused<<<BB * HH, 256, 0, stream>>>(qkv, AO);

  // proj: proven round-3 structure (145 x 8) — in-run control
  gemm_bt2<<<145 * 8, 256, 0, stream>>>(AO, Wpb, nullptr, (float*)d_out, bproj,
                                        MM, CC, CC, 145, 8);
}

// Round 13
// 277.278 us; speedup vs baseline: 1.6730x; 1.0283x over previous
//
#include <hip/hip_runtime.h>

typedef unsigned short u16;
typedef u16 u16x8 __attribute__((ext_vector_type(8)));
typedef u16 u16x4 __attribute__((ext_vector_type(4)));
typedef __bf16 bf16x8 __attribute__((ext_vector_type(8)));
typedef float f32x4 __attribute__((ext_vector_type(4)));

#define DEVI static __device__ __forceinline__

#define BB 32
#define NN 577
#define CC 1024
#define HH 16
#define DD 64
#define MM (BB * NN)   // 18464
#define SCALE_ 0.125f

DEVI u16 f2bf(float f) {
  union { float f; unsigned u; } v; v.f = f;
  unsigned r = v.u + 0x7FFFu + ((v.u >> 16) & 1u);
  return (u16)(r >> 16);
}
DEVI float bf2f(u16 b) {
  union { unsigned u; float f; } v; v.u = ((unsigned)b) << 16; return v.f;
}
DEVI f32x4 mfma16(u16x8 a, u16x8 b, f32x4 c) {
  return __builtin_amdgcn_mfma_f32_16x16x32_bf16(
      __builtin_bit_cast(bf16x8, a), __builtin_bit_cast(bf16x8, b), c, 0, 0, 0);
}
DEVI void gload_lds16(const u16* g, u16* l) {
  __builtin_amdgcn_global_load_lds(
      (const __attribute__((address_space(1))) void*)g,
      (__attribute__((address_space(3))) void*)l, 16, 0, 0);
}
DEVI void fencec() { asm volatile("" ::: "memory"); }
DEVI void lbar() { fencec(); __builtin_amdgcn_s_barrier(); fencec(); }

// ---------------- fused fp32 -> bf16 convert (X, Wqkv, Wproj) ----------------
__global__ void cvt3_kernel(const float* __restrict__ X, const float* __restrict__ Wq,
                            const float* __restrict__ Wp, u16* __restrict__ Xb,
                            u16* __restrict__ Wqb, u16* __restrict__ Wpb) {
  const int nX = (MM * CC) / 4;
  const int nQ = (3 * CC * CC) / 4;
  const int nP = (CC * CC) / 4;
  const int total = nX + nQ + nP;
  int i = blockIdx.x * blockDim.x + threadIdx.x;
  int stride = gridDim.x * blockDim.x;
  for (; i < total; i += stride) {
    const float* in; u16* out; int k;
    if (i < nX)            { in = X;  out = Xb;  k = i; }
    else if (i < nX + nQ)  { in = Wq; out = Wqb; k = i - nX; }
    else                   { in = Wp; out = Wpb; k = i - nX - nQ; }
    float4 v = ((const float4*)in)[k];
    u16x4 o = { f2bf(v.x), f2bf(v.y), f2bf(v.z), f2bf(v.w) };
    ((u16x4*)out)[k] = o;
  }
}

// ======== 2-phase staggered GEMM: 256x256, BK=64, 8 waves, 2-dbuf ===========
// A/B of round-12's 4-phase schedule with phases MERGED (4 barriers/K-tile
// instead of 8). Same staggered prefetch (B: 2 phases ahead; A: 4 phases
// ahead), same counted vmcnt(4).
// Per K-tile T (cur=T&1, nxt=cur^1):
//  P0: read aL(8)+aH(8)+bL(4); stage B(T+1)->nxt (4); bar; 32 MFMA Q0+Q1; bar
//  P1: read bH(4);             stage A(T+2)->cur (4); bar; 32 MFMA Q2+Q3;
//      vmcnt(4); bar
// vmcnt ledger (FIFO): issue order ...A(T+1)[T-1.P1], B(T+1)[T.P0],
// A(T+2)[T.P1]. At T's end <=4 outstanding => A(T+1),B(T+1) retired,
// A(T+2) in flight. WAR: every staged region's last ds_read completed
// (lgkmcnt before its MFMA) at least one barrier earlier.
__global__ __launch_bounds__(512, 1) void gemm_2p(
    const u16* __restrict__ A, const u16* __restrict__ Bw,
    u16* __restrict__ Cb, int M, int N, int K, int MT, int NT)
{
  __shared__ u16 Als[2][16384];   // 64 KB
  __shared__ u16 Bls[2][16384];   // 64 KB

  // bijective XCD swizzle (m204)
  int nwg = MT * NT;
  int orig = blockIdx.x;
  int q = nwg >> 3, r = nwg & 7;
  int xcd = orig & 7, idx = orig >> 3;
  int wg = (xcd < r ? xcd * (q + 1) : r * (q + 1) + (xcd - r) * q) + idx;
  int mt = wg / NT, nt = wg % NT;

  const int t = threadIdx.x, lane = t & 63, w = t >> 6;
  const int wr2 = w >> 2, wc2 = w & 3;      // 2(M) x 4(N) wave grid
  const int fr = lane & 15, fg = lane >> 4;
  const int m0 = mt * 256, n0 = nt * 256;

  f32x4 acc[8][4] = {};

  const int swcol = ((lane & 7) ^ ((lane >> 3) & 7)) * 8;
  const u16* pA[2][2];
  const u16* pB[2][2];
#pragma unroll
  for (int h = 0; h < 2; ++h)
#pragma unroll
    for (int j = 0; j < 2; ++j) {
      int row = h * 128 + (w * 2 + j) * 8 + (lane >> 3);
      int ga = m0 + row; if (ga > M - 1) ga = M - 1;
      pA[h][j] = A + (size_t)ga * K + swcol;
      pB[h][j] = Bw + (size_t)(n0 + row) * K + swcol;   // N % 256 == 0
    }
  const int lofs = (w * 2) * 512;

  auto stageA = [&](int tile, int buf) {
    const int kc = tile << 6;
#pragma unroll
    for (int h = 0; h < 2; ++h) {
      gload_lds16(pA[h][0] + kc, &Als[buf][h * 8192 + lofs]);
      gload_lds16(pA[h][1] + kc, &Als[buf][h * 8192 + lofs + 512]);
    }
  };
  auto stageB = [&](int tile, int buf) {
    const int kc = tile << 6;
#pragma unroll
    for (int h = 0; h < 2; ++h) {
      gload_lds16(pB[h][0] + kc, &Bls[buf][h * 8192 + lofs]);
      gload_lds16(pB[h][1] + kc, &Bls[buf][h * 8192 + lofs + 512]);
    }
  };

  const int chk[2] = { ((0 * 4 + fg) ^ (fr & 7)) * 8, ((1 * 4 + fg) ^ (fr & 7)) * 8 };
  const int arow = wr2 * 128 + fr;   // + m*16
  const int brow = wc2 * 64 + fr;    // + n*16

  const int nkt = K >> 6;   // 16

  // prologue: tile0 (A+B) + A(1) in flight; vmcnt(4) retires tile0's 8 loads
  stageA(0, 0);
  stageB(0, 0);
  stageA(1, 1);
  asm volatile("s_waitcnt vmcnt(4)" ::: "memory");
  lbar();

  u16x8 aL[4][2], aH[4][2], bL[2][2], bH[2][2];

  for (int T = 0; T < nkt; ++T) {
    const int cur = T & 1, nxt = cur ^ 1;
    const u16* Ac = &Als[cur][0];
    const u16* Bc = &Bls[cur][0];
    const bool s1 = (T + 1 < nkt), s2 = (T + 2 < nkt);

    // ---- P0: aL+aH+bL reads; stage B(T+1); MFMA Q0+Q1 ----
#pragma unroll
    for (int m = 0; m < 4; ++m)
#pragma unroll
      for (int kk = 0; kk < 2; ++kk) {
        aL[m][kk] = *(const u16x8*)&Ac[(arow + m * 16) * 64 + chk[kk]];
        aH[m][kk] = *(const u16x8*)&Ac[(arow + (m + 4) * 16) * 64 + chk[kk]];
      }
#pragma unroll
    for (int n = 0; n < 2; ++n)
#pragma unroll
      for (int kk = 0; kk < 2; ++kk)
        bL[n][kk] = *(const u16x8*)&Bc[(brow + n * 16) * 64 + chk[kk]];
    if (s1) stageB(T + 1, nxt);
    lbar();
    __builtin_amdgcn_s_setprio(1);
#pragma unroll
    for (int m = 0; m < 4; ++m)
#pragma unroll
      for (int n = 0; n < 2; ++n)
#pragma unroll
        for (int kk = 0; kk < 2; ++kk) {
          acc[m][n]     = mfma16(aL[m][kk], bL[n][kk], acc[m][n]);
          acc[m + 4][n] = mfma16(aH[m][kk], bL[n][kk], acc[m + 4][n]);
        }
    __builtin_amdgcn_s_setprio(0);
    lbar();

    // ---- P1: bH reads; stage A(T+2); MFMA Q2+Q3; counted vmcnt ----
#pragma unroll
    for (int n = 0; n < 2; ++n)
#pragma unroll
      for (int kk = 0; kk < 2; ++kk)
        bH[n][kk] = *(const u16x8*)&Bc[(brow + (n + 2) * 16) * 64 + chk[kk]];
    if (s2) stageA(T + 2, cur);
    lbar();
    __builtin_amdgcn_s_setprio(1);
#pragma unroll
    for (int m = 0; m < 4; ++m)
#pragma unroll
      for (int n = 0; n < 2; ++n)
#pragma unroll
        for (int kk = 0; kk < 2; ++kk) {
          acc[m][n + 2]     = mfma16(aL[m][kk], bH[n][kk], acc[m][n + 2]);
          acc[m + 4][n + 2] = mfma16(aH[m][kk], bH[n][kk], acc[m + 4][n + 2]);
        }
    __builtin_amdgcn_s_setprio(0);
    if (s2) asm volatile("s_waitcnt vmcnt(4)" ::: "memory");
    else    asm volatile("s_waitcnt vmcnt(0)" ::: "memory");
    lbar();
  }

  // epilogue
#pragma unroll
  for (int m = 0; m < 8; ++m) {
#pragma unroll
    for (int j = 0; j < 4; ++j) {
      int row = m0 + wr2 * 128 + m * 16 + fg * 4 + j;
      if (row >= M) continue;
#pragma unroll
      for (int n = 0; n < 4; ++n) {
        int col = n0 + wc2 * 64 + n * 16 + fr;
        Cb[(size_t)row * N + col] = f2bf(acc[m][n][j]);
      }
    }
  }
}

// ---------------- GEMM (round-3 m97 structure + T2 swizzle) -----------------
__global__ __launch_bounds__(256) void gemm_bt2(
    const u16* __restrict__ A, const u16* __restrict__ Bw,
    u16* __restrict__ Cb, float* __restrict__ Cf, const float* __restrict__ bias,
    int M, int N, int K, int MT, int NT)
{
  __shared__ u16 Als[128 * 64];
  __shared__ u16 Bls[128 * 64];

  int nwg = MT * NT;
  int orig = blockIdx.x;
  int q = nwg >> 3, r = nwg & 7;
  int xcd = orig & 7, idx = orig >> 3;
  int wg = (xcd < r ? xcd * (q + 1) : r * (q + 1) + (xcd - r) * q) + idx;
  int mt = wg / NT, nt = wg % NT;

  const int t = threadIdx.x, lane = t & 63, w = t >> 6;
  const int wr = (w >> 1) * 64, wc = (w & 1) * 64;
  const int fr = lane & 15, fg = lane >> 4;
  const int m0 = mt * 128, n0 = nt * 128;
  f32x4 acc[4][4] = {};

  const int swcol = ((lane & 7) ^ ((lane >> 3) & 7)) * 8;
  const u16* pA[4];
  const u16* pB[4];
#pragma unroll
  for (int i = 0; i < 4; ++i) {
    int row = w * 32 + i * 8 + (lane >> 3);
    int ga = m0 + row; if (ga > M - 1) ga = M - 1;
    pA[i] = A + (size_t)ga * K + swcol;
    pB[i] = Bw + (size_t)(n0 + row) * K + swcol;
  }

  for (int kt = 0; kt < K; kt += 64) {
#pragma unroll
    for (int i = 0; i < 4; ++i) {
      int c = w * 4 + i;
      gload_lds16(pA[i] + kt, &Als[c * 512]);
      gload_lds16(pB[i] + kt, &Bls[c * 512]);
    }
    __syncthreads();
#pragma unroll
    for (int kk = 0; kk < 2; ++kk) {
      u16x8 af[4], bfr[4];
#pragma unroll
      for (int m = 0; m < 4; ++m) {
        int row = wr + m * 16 + fr;
        int ch = (kk * 4 + fg) ^ (fr & 7);
        af[m] = *(const u16x8*)&Als[row * 64 + ch * 8];
      }
#pragma unroll
      for (int n = 0; n < 4; ++n) {
        int row = wc + n * 16 + fr;
        int ch = (kk * 4 + fg) ^ (fr & 7);
        bfr[n] = *(const u16x8*)&Bls[row * 64 + ch * 8];
      }
#pragma unroll
      for (int m = 0; m < 4; ++m)
#pragma unroll
        for (int n = 0; n < 4; ++n)
          acc[m][n] = mfma16(af[m], bfr[n], acc[m][n]);
    }
    __syncthreads();
  }

#pragma unroll
  for (int m = 0; m < 4; ++m) {
#pragma unroll
    for (int j = 0; j < 4; ++j) {
      int row = m0 + wr + m * 16 + fg * 4 + j;
      if (row >= M) continue;
#pragma unroll
      for (int n = 0; n < 4; ++n) {
        int col = n0 + wc + n * 16 + fr;
        float v = acc[m][n][j];
        if (Cf) Cf[(size_t)row * N + col] = v + bias[col];
        else    Cb[(size_t)row * N + col] = f2bf(v);
      }
    }
  }
}

// ======== fused attention: pool + stage1 + stage2 (one block per (b,h)) =====
__global__ __launch_bounds__(256) void attn_fused(
    const u16* __restrict__ qkv, u16* __restrict__ AO)
{
  __shared__ u16 Qp[64][72];
  __shared__ u16 Qd[64][72];
  __shared__ u16 Kls[64][72];
  __shared__ u16 Vt[64][72];
  __shared__ u16 Pls[4][16][72];

  int bh = blockIdx.x, b = bh >> 4, h = bh & 15;
  int t = threadIdx.x, lane = t & 63, w = t >> 6;
  int fr = lane & 15, fg = lane >> 4;

  // ---- pool ----
  {
    int pq = t >> 2, d0 = (t & 3) * 16;
    int py = pq >> 3, px = pq & 7;
    float s[16] = {};
#pragma unroll
    for (int dy = 0; dy < 3; ++dy)
#pragma unroll
      for (int dx = 0; dx < 3; ++dx) {
        int n = (py * 3 + dy) * 24 + px * 3 + dx;
        const u16* p = qkv + (size_t)(b * NN + n) * 3072 + h * DD + d0;
        u16x8 v0 = *(const u16x8*)p;
        u16x8 v1 = *(const u16x8*)(p + 8);
#pragma unroll
        for (int j = 0; j < 8; ++j) { s[j] += bf2f(v0[j]); s[8 + j] += bf2f(v1[j]); }
      }
    const float rinv = 1.f / 9.f;
    u16x8 o0, o1;
#pragma unroll
    for (int j = 0; j < 8; ++j) { o0[j] = f2bf(s[j] * rinv); o1[j] = f2bf(s[8 + j] * rinv); }
    *(u16x8*)&Qp[pq][d0] = o0;
    *(u16x8*)&Qp[pq][d0 + 8] = o1;
  }
  __syncthreads();

  // ---- stage 1 ----
  {
    u16x8 qf0 = *(const u16x8*)&Qp[w * 16 + fr][fg * 8];
    u16x8 qf1 = *(const u16x8*)&Qp[w * 16 + fr][32 + fg * 8];

    f32x4 o[4] = {};
    float rowm[4] = {-1e30f, -1e30f, -1e30f, -1e30f};
    float rowl[4] = {};

    for (int kt = 0; kt < 10; ++kt) {
#pragma unroll
      for (int i = 0; i < 2; ++i) {
        int g = t + i * 256;
        int key = g >> 3, cc = (g & 7) * 8;
        int n = kt * 64 + key;
        u16x8 kv = {}, vv = {};
        if (n < NN) {
          const u16* p = qkv + (size_t)(b * NN + n) * 3072 + h * DD + cc;
          kv = *(const u16x8*)(p + CC);
          vv = *(const u16x8*)(p + 2 * CC);
        }
        *(u16x8*)&Kls[key][cc] = kv;
#pragma unroll
        for (int j = 0; j < 8; ++j) Vt[cc + j][key] = vv[j];
      }
      __syncthreads();

      f32x4 s[4] = {};
#pragma unroll
      for (int kk = 0; kk < 2; ++kk) {
        u16x8 qf = kk ? qf1 : qf0;
#pragma unroll
        for (int n = 0; n < 4; ++n) {
          u16x8 kf = *(const u16x8*)&Kls[n * 16 + fr][kk * 32 + fg * 8];
          s[n] = mfma16(qf, kf, s[n]);
        }
      }
      float mx[4] = {-1e30f, -1e30f, -1e30f, -1e30f};
#pragma unroll
      for (int n = 0; n < 4; ++n) {
        int key = kt * 64 + n * 16 + fr;
#pragma unroll
        for (int j = 0; j < 4; ++j) {
          float v = s[n][j] * SCALE_;
          if (key >= NN) v = -1e30f;
          s[n][j] = v;
          mx[j] = fmaxf(mx[j], v);
        }
      }
      for (int d = 1; d < 16; d <<= 1) {
#pragma unroll
        for (int j = 0; j < 4; ++j) mx[j] = fmaxf(mx[j], __shfl_xor(mx[j], d));
      }
      float corr[4];
#pragma unroll
      for (int j = 0; j < 4; ++j) {
        float mn = fmaxf(rowm[j], mx[j]);
        corr[j] = __expf(rowm[j] - mn);
        rowm[j] = mn;
      }
      float rs[4] = {};
#pragma unroll
      for (int n = 0; n < 4; ++n)
#pragma unroll
        for (int j = 0; j < 4; ++j) {
          float p = __expf(s[n][j] - rowm[j]);
          s[n][j] = p;
          rs[j] += p;
        }
      for (int d = 1; d < 16; d <<= 1) {
#pragma unroll
        for (int j = 0; j < 4; ++j) rs[j] += __shfl_xor(rs[j], d);
      }
#pragma unroll
      for (int j = 0; j < 4; ++j) rowl[j] = rowl[j] * corr[j] + rs[j];
#pragma unroll
      for (int n = 0; n < 4; ++n)
#pragma unroll
        for (int j = 0; j < 4; ++j) o[n][j] *= corr[j];

#pragma unroll
      for (int n = 0; n < 4; ++n)
#pragma unroll
        for (int j = 0; j < 4; ++j)
          Pls[w][fg * 4 + j][n * 16 + fr] = f2bf(s[n][j]);

#pragma unroll
      for (int kk = 0; kk < 2; ++kk) {
        u16x8 pf = *(const u16x8*)&Pls[w][fr][kk * 32 + fg * 8];
#pragma unroll
        for (int n = 0; n < 4; ++n) {
          u16x8 vf = *(const u16x8*)&Vt[n * 16 + fr][kk * 32 + fg * 8];
          o[n] = mfma16(pf, vf, o[n]);
        }
      }
      __syncthreads();
    }

#pragma unroll
    for (int n = 0; n < 4; ++n)
#pragma unroll
      for (int j = 0; j < 4; ++j)
        Qd[n * 16 + fr][w * 16 + fg * 4 + j] = f2bf(o[n][j] / rowl[j]);
  }
  __syncthreads();

  // ---- stage 2 ----
  u16x8 bq[2][4], dq[2][4];
#pragma unroll
  for (int kk = 0; kk < 2; ++kk)
#pragma unroll
    for (int n = 0; n < 4; ++n) {
      bq[kk][n] = *(const u16x8*)&Qp[n * 16 + fr][kk * 32 + fg * 8];
      dq[kk][n] = *(const u16x8*)&Qd[n * 16 + fr][kk * 32 + fg * 8];
    }

  for (int nt = 0; nt < 10; ++nt) {
    int n0 = nt * 64;
    int qrow = n0 + w * 16 + fr;
    int qc = qrow < NN ? qrow : NN - 1;
    const u16* Qb = qkv + (size_t)(b * NN + qc) * 3072 + h * DD;
    u16x8 a0 = *(const u16x8*)(Qb + fg * 8);
    u16x8 a1 = *(const u16x8*)(Qb + 32 + fg * 8);

    f32x4 s[4] = {};
#pragma unroll
    for (int n = 0; n < 4; ++n) {
      s[n] = mfma16(a0, bq[0][n], s[n]);
      s[n] = mfma16(a1, bq[1][n], s[n]);
    }
    float mx[4] = {-1e30f, -1e30f, -1e30f, -1e30f};
#pragma unroll
    for (int n = 0; n < 4; ++n)
#pragma unroll
      for (int j = 0; j < 4; ++j) {
        float v = s[n][j] * SCALE_;
        s[n][j] = v;
        mx[j] = fmaxf(mx[j], v);
      }
    for (int d = 1; d < 16; d <<= 1) {
#pragma unroll
      for (int j = 0; j < 4; ++j) mx[j] = fmaxf(mx[j], __shfl_xor(mx[j], d));
    }
    float rs[4] = {};
#pragma unroll
    for (int n = 0; n < 4; ++n)
#pragma unroll
      for (int j = 0; j < 4; ++j) {
        float p = __expf(s[n][j] - mx[j]);
        s[n][j] = p;
        rs[j] += p;
      }
    for (int d = 1; d < 16; d <<= 1) {
#pragma unroll
      for (int j = 0; j < 4; ++j) rs[j] += __shfl_xor(rs[j], d);
    }

#pragma unroll
    for (int n = 0; n < 4; ++n)
#pragma unroll
      for (int j = 0; j < 4; ++j)
        Pls[w][fg * 4 + j][n * 16 + fr] = f2bf(s[n][j]);

    f32x4 of[4] = {};
#pragma unroll
    for (int kk = 0; kk < 2; ++kk) {
      u16x8 pf = *(const u16x8*)&Pls[w][fr][kk * 32 + fg * 8];
#pragma unroll
      for (int n = 0; n < 4; ++n)
        of[n] = mfma16(pf, dq[kk][n], of[n]);
    }

#pragma unroll
    for (int n = 0; n < 4; ++n)
#pragma unroll
      for (int j = 0; j < 4; ++j) {
        int orow = n0 + w * 16 + fg * 4 + j;
        if (orow < NN)
          AO[(size_t)(b * NN + orow) * CC + h * DD + n * 16 + fr] = f2bf(of[n][j] / rs[j]);
      }
  }
}

// ---------------- launch ----------------
extern "C" void kernel_launch(void* const* d_in, const int* in_sizes, int n_in,
                              void* d_out, int out_size, void* d_ws, size_t ws_size,
                              hipStream_t stream) {
  const float* X     = (const float*)d_in[0];
  const float* Wqkv  = (const float*)d_in[1];
  const float* Wproj = (const float*)d_in[2];
  const float* bproj = (const float*)d_in[3];

  char* ws = (char*)d_ws;
  u16* Xb  = (u16*)(ws + 0);            // 18464*1024*2 = 37,814,272
  u16* Wqb = (u16*)(ws + 37814272);     // 3072*1024*2  =  6,291,456
  u16* Wpb = (u16*)(ws + 44105728);     // 1024*1024*2  =  2,097,152
  u16* qkv = (u16*)(ws + 46202880);     // 18464*3072*2 = 113,442,816
  u16* AO  = (u16*)(ws + 159645696);    // 18464*1024*2 = 37,814,272

  cvt3_kernel<<<2048, 256, 0, stream>>>(X, Wqkv, Wproj, Xb, Wqb, Wpb);

  // QKV: 2-phase staggered 256x256 (73 x 12 = 876 blocks)
  gemm_2p<<<73 * 12, 512, 0, stream>>>(Xb, Wqb, qkv, MM, 3 * CC, CC, 73, 12);

  attn_fused<<<BB * HH, 256, 0, stream>>>(qkv, AO);

  // proj: proven round-3 structure (145 x 8) — in-run control
  gemm_bt2<<<145 * 8, 256, 0, stream>>>(AO, Wpb, nullptr, (float*)d_out, bproj,
                                        MM, CC, CC, 145, 8);
}